// Round 9
// baseline (928.222 us; speedup 1.0000x reference)
//
#include <hip/hip_runtime.h>
#include <hip/hip_bf16.h>
#include <math.h>

// Problem constants (fixed by setup_inputs)
#define BATCH 16
#define LEN   262144
#define HOP   256
#define PADW  512          // n_fft/2
#define NFREQ 513          // rfft bins
#define NFRM  1025         // frames
#define NPAIR 513          // frame pairs (2 frames per FFT)
#define NPT   65           // time patches
#define NPF   33           // freq patches
#define NPATCH 2145        // 33*65
#define TOPK  643          // int(2145*0.3)
#define EPSV  1e-8f
#define NBLOCKS (NPAIR * BATCH)   // 8208

// LDS bank-conflict swizzle: float2 element i lives at phys i^((i>>4)&15).
// NOTE: for j<4 and i0=4t, SW(i0+j) = SW(i0) ^ j (XOR, not +j — R7 bug).
#define SW(i) ((i) ^ (((i) >> 4) & 15))

// Shared memory: FFT phase needs xs[1024] float2 (8192 B) + tw[256] float2
// (2048 B) = 10240 B. Winner-topk phase reuses the same buffer:
//   ukey[2145] u32 @0, plv[2145] f32 @8580, tIdx[2145] u16 @17160,
//   hist[256] u32 @21452, wtot[4] @22476, tcnt @22492, selB @22496,
//   selHi @22500, red[3][4] @22504..22552.
#define SMEM_BYTES 23552

__device__ __forceinline__ int reflect_idx(int g) {
    g = (g < 0) ? -g : g;
    g = (g >= LEN) ? (2 * LEN - 2 - g) : g;
    return g;
}

__device__ __forceinline__ void load_pack_edge(float2* xs,
    const float* __restrict__ re_src, const float* __restrict__ im_src,
    int startRe, int startIm, int tid)
{
    #pragma unroll
    for (int m = 0; m < 4; ++m) {
        const int i = tid + 256 * m;
        xs[SW(i)] = make_float2(re_src[reflect_idx(startRe + i)],
                                im_src[reflect_idx(startIm + i)]);
    }
    __syncthreads();
}

__device__ __forceinline__ void load_pack_fast(float2* xs,
    const float* __restrict__ re_src, const float* __restrict__ im_src,
    int startRe, int startIm, int tid)
{
    const float4 r4 = *reinterpret_cast<const float4*>(re_src + startRe + 4 * tid);
    const float4 i4 = *reinterpret_cast<const float4*>(im_src + startIm + 4 * tid);
    const int base = SW(4 * tid);
    xs[base ^ 0] = make_float2(r4.x, i4.x);   // SW(4t+j) = SW(4t) ^ j
    xs[base ^ 1] = make_float2(r4.y, i4.y);
    xs[base ^ 2] = make_float2(r4.z, i4.z);
    xs[base ^ 3] = make_float2(r4.w, i4.w);
    __syncthreads();
}

// 1024-pt radix-4 DIF complex FFT. Natural input, base-4 digit-reversed output.
__device__ __forceinline__ void fft1024(float2* xs, const float2* tw, float2 w0, int tid) {
    #pragma unroll
    for (int s = 0; s < 5; ++s) {
        const int lenlog = 10 - 2 * s;
        const int q      = 1 << (lenlog - 2);
        const int pos    = tid & (q - 1);
        const int blk    = tid >> (lenlog - 2);
        const int i0     = (blk << lenlog) + pos;

        float2 a  = xs[SW(i0)];
        float2 bb = xs[SW(i0 + q)];
        float2 c  = xs[SW(i0 + 2 * q)];
        float2 d  = xs[SW(i0 + 3 * q)];

        const float t0x = a.x + c.x,  t0y = a.y + c.y;
        const float t1x = a.x - c.x,  t1y = a.y - c.y;
        const float t2x = bb.x + d.x, t2y = bb.y + d.y;
        const float t3x = bb.x - d.x, t3y = bb.y - d.y;

        const float y0x = t0x + t2x, y0y = t0y + t2y;
        const float y1x = t1x + t3y, y1y = t1y - t3x;
        const float y2x = t0x - t2x, y2y = t0y - t2y;
        const float y3x = t1x - t3y, y3y = t1y + t3x;

        if (s == 4) {
            const int o = SW(i0);
            xs[o ^ 0] = make_float2(y0x, y0y);
            xs[o ^ 1] = make_float2(y1x, y1y);
            xs[o ^ 2] = make_float2(y2x, y2y);
            xs[o ^ 3] = make_float2(y3x, y3y);
        } else {
            const float2 w1 = (s == 0) ? w0 : tw[SW(pos << (2 * s))];
            const float2 w2 = make_float2(w1.x * w1.x - w1.y * w1.y, 2.0f * w1.x * w1.y);
            const float2 w3 = make_float2(w2.x * w1.x - w2.y * w1.y, w2.x * w1.y + w2.y * w1.x);
            xs[SW(i0)]         = make_float2(y0x, y0y);
            xs[SW(i0 + q)]     = make_float2(y1x * w1.x - y1y * w1.y, y1x * w1.y + y1y * w1.x);
            xs[SW(i0 + 2 * q)] = make_float2(y2x * w2.x - y2y * w2.y, y2x * w2.y + y2y * w2.x);
            xs[SW(i0 + 3 * q)] = make_float2(y3x * w3.x - y3y * w3.y, y3x * w3.y + y3y * w3.x);
        }
        __syncthreads();
    }
}

__device__ __forceinline__ void unpack_k(const float2* xs, int k,
                                         float& mx, float& my)
{
    const unsigned rk = __brev((unsigned)k) >> 22;
    const unsigned pk = ((rk & 0x155u) << 1) | ((rk & 0x2AAu) >> 1);
    const unsigned mI = (unsigned)(1024 - k) & 1023u;
    const unsigned rm = __brev(mI) >> 22;
    const unsigned pm = ((rm & 0x155u) << 1) | ((rm & 0x2AAu) >> 1);
    const float2 Zk = xs[SW(pk)];
    const float2 Zm = xs[SW(pm)];
    const float ar = Zk.x + Zm.x, ai = Zk.y - Zm.y;   // 2*X[k]
    const float br = Zk.y + Zm.y, bi = Zk.x - Zm.x;   // 2*Y[k]
    mx = fmaxf(0.5f * sqrtf(ar * ar + ai * ai), EPSV);
    my = fmaxf(0.5f * sqrtf(br * br + bi * bi), EPSV);
}

// ---------------------------------------------------------------------------
// Winner-block topk for one batch row (256 threads). Radix select with jax
// tie-break; atomically accumulates the 3 averaged outputs into out[].
// ---------------------------------------------------------------------------
__device__ void row_topk(const float* __restrict__ part, int row, char* smem,
                         float* __restrict__ out, int tid)
{
    unsigned*       ukey = (unsigned*)(smem);
    float*          plv  = (float*)(smem + 8580);
    unsigned short* tIdx = (unsigned short*)(smem + 17160);
    unsigned*       hist = (unsigned*)(smem + 21452);
    unsigned*       wtot = (unsigned*)(smem + 22476);
    int*            tcnt = (int*)(smem + 22492);
    unsigned*       selB = (unsigned*)(smem + 22496);
    unsigned*       selHi= (unsigned*)(smem + 22500);
    float*          red  = (float*)(smem + 22504);   // [3][4]

    // Phase A: combine pair partials -> key + patch_loss.
    float lsum = 0.0f, lpos = 0.0f;
    for (int p2 = tid; p2 < NPATCH; p2 += 256) {
        const int fi = p2 / NPT;
        const int ti = p2 - fi * NPT;
        const float* base = part + (((size_t)row * NPF + fi) * NPAIR + ti * 8) * 3;
        float a = 0.0f, t3 = 0.0f, q = 0.0f;
        #pragma unroll
        for (int u = 0; u < 8; ++u) {
            if (ti * 8 + u < NPAIR) {
                a  += base[u * 3 + 0];
                t3 += base[u * 3 + 1];
                q  += base[u * 3 + 2];
            }
        }
        const float kg = (a - t3) * (1.0f / 256.0f);
        lsum += kg;
        lpos += (kg > 0.0f) ? 1.0f : 0.0f;
        plv[p2] = q * (1.0f / 256.0f);
        unsigned u32 = __float_as_uint(kg);
        ukey[p2] = (u32 & 0x80000000u) ? ~u32 : (u32 | 0x80000000u);
    }
    if (tid == 0) *tcnt = 0;
    __syncthreads();

    // Phase B: 8-bit MSB radix select.
    unsigned prefix = 0;
    int rem = TOPK;
    #pragma unroll
    for (int pass = 0; pass < 4; ++pass) {
        const int shift = 24 - 8 * pass;
        const unsigned himask = (pass == 0) ? 0u : (0xFFFFFFFFu << (shift + 8));

        hist[tid] = 0;
        __syncthreads();
        for (int i = tid; i < NPATCH; i += 256) {
            unsigned u = ukey[i];
            if ((u & himask) == (prefix & himask))
                atomicAdd(&hist[(u >> shift) & 255u], 1u);
        }
        __syncthreads();

        const unsigned h = hist[tid];
        unsigned v = h;
        const int lane = tid & 63;
        const int w    = tid >> 6;
        #pragma unroll
        for (int off = 1; off < 64; off <<= 1) {
            unsigned tval = __shfl_down(v, off);
            if (lane + off < 64) v += tval;
        }
        if (lane == 0) wtot[w] = v;
        __syncthreads();
        unsigned addv = 0;
        for (int w2 = w + 1; w2 < 4; ++w2) addv += wtot[w2];
        v += addv;                    // suffix sum over bins >= tid
        const unsigned hi = v - h;    // suffix sum over bins >  tid
        if (v >= (unsigned)rem && hi < (unsigned)rem) { *selB = (unsigned)tid; *selHi = hi; }
        __syncthreads();
        prefix |= (*selB << shift);
        rem -= (int)*selHi;
        __syncthreads();
    }

    // Phase C: selected sums (ties at T resolved by lowest index — jax order).
    const unsigned T = prefix;
    float ssum = 0.0f;
    for (int i = tid; i < NPATCH; i += 256) {
        unsigned u = ukey[i];
        if (u > T) {
            ssum += plv[i];
        } else if (u == T) {
            int j = atomicAdd(tcnt, 1);
            tIdx[j] = (unsigned short)i;
        }
    }
    __syncthreads();
    const int m = *tcnt;
    if (m == rem) {
        for (int j = tid; j < m; j += 256) ssum += plv[tIdx[j]];
    } else {
        for (int j = tid; j < m; j += 256) {
            const int i = tIdx[j];
            int rank = 0;
            for (int q = 0; q < m; ++q) rank += (tIdx[q] < i) ? 1 : 0;
            if (rank < rem) ssum += plv[i];
        }
    }

    #pragma unroll
    for (int off = 32; off > 0; off >>= 1) {
        ssum += __shfl_down(ssum, off);
        lsum += __shfl_down(lsum, off);
        lpos += __shfl_down(lpos, off);
    }
    if ((tid & 63) == 0) {
        const int wv = tid >> 6;
        red[0 * 4 + wv] = ssum; red[1 * 4 + wv] = lsum; red[2 * 4 + wv] = lpos;
    }
    __syncthreads();
    if (tid == 0) {
        float a = red[0] + red[1] + red[2] + red[3];
        float c = red[4] + red[5] + red[6] + red[7];
        float d = red[8] + red[9] + red[10] + red[11];
        atomicAdd(&out[0], a * (1.0f / ((float)TOPK * (float)BATCH)));
        atomicAdd(&out[2], c * (1.0f / ((float)BATCH * (float)NPATCH)));
        atomicAdd(&out[3], d * (1.0f / ((float)BATCH * (float)NPATCH)));
        if (row == 0) out[1] = (float)TOPK / (float)NPATCH;
    }
}

// ---------------------------------------------------------------------------
// Single fused kernel: STFT + patch-partials (all blocks), then the last 16
// blocks to finish each run one row's top-k and accumulate the outputs.
// ---------------------------------------------------------------------------
__global__ __launch_bounds__(256) void fused_stft_topk_kernel(
    const float* __restrict__ s_in, const float* __restrict__ t_in,
    const float* __restrict__ g_in,
    float* __restrict__ part, unsigned* __restrict__ counter,
    float* __restrict__ out)
{
    __shared__ __align__(16) char smem[SMEM_BYTES];
    __shared__ int myrow;
    float2* xs = (float2*)smem;
    float2* tw = (float2*)(smem + 8192);

    const int tid = threadIdx.x;
    const int p   = blockIdx.x;   // 0..512
    const int b   = blockIdx.y;   // 0..15

    const float* sp = s_in + (size_t)b * LEN;
    const float* tp = t_in + (size_t)b * LEN;
    const float* gp = g_in + (size_t)b * LEN;

    float2 w0;
    {
        float sv, cv;
        sincosf(-6.283185307179586476925f * (float)tid * (1.0f / 1024.0f), &sv, &cv);
        w0 = make_float2(cv, sv);
        tw[SW(tid)] = w0;
    }

    const bool hasB  = (2 * p + 1) < NFRM;
    const bool fast  = (p >= 1) && (p <= 510);
    const int startA = 2 * p * HOP - PADW;
    const int startB = startA + HOP;

    float sA[3], tA[3], sB[3], tB[3];

    if (fast) load_pack_fast(xs, sp, tp, startA, startA, tid);
    else      load_pack_edge(xs, sp, tp, startA, startA, tid);
    fft1024(xs, tw, w0, tid);
    #pragma unroll
    for (int it = 0; it < 3; ++it) {
        const int k = tid + 256 * it;
        sA[it] = 0.0f; tA[it] = 0.0f;
        if (k <= 512) unpack_k(xs, k, sA[it], tA[it]);
    }
    __syncthreads();

    if (fast) load_pack_fast(xs, sp, tp, startB, startB, tid);
    else      load_pack_edge(xs, sp, tp, startB, startB, tid);
    fft1024(xs, tw, w0, tid);
    #pragma unroll
    for (int it = 0; it < 3; ++it) {
        const int k = tid + 256 * it;
        sB[it] = 0.0f; tB[it] = 0.0f;
        if (k <= 512) unpack_k(xs, k, sB[it], tB[it]);
    }
    __syncthreads();

    if (fast) load_pack_fast(xs, gp, gp, startA, startB, tid);
    else      load_pack_edge(xs, gp, gp, startA, startB, tid);
    fft1024(xs, tw, w0, tid);

    #pragma unroll
    for (int it = 0; it < 3; ++it) {
        const int k = tid + 256 * it;
        const bool valid = (k <= 512);
        float as = 0.0f, at = 0.0f, sq = 0.0f;
        if (valid) {
            float gA_, gB_;
            unpack_k(xs, k, gA_, gB_);
            as = fabsf(sA[it] - gA_);
            at = fabsf(tA[it] - gA_);
            sq = (sA[it] - tA[it]) * (sA[it] - tA[it]);
            if (hasB) {
                as += fabsf(sB[it] - gB_);
                at += fabsf(tB[it] - gB_);
                sq += (sB[it] - tB[it]) * (sB[it] - tB[it]);
            }
        }
        #pragma unroll
        for (int off = 8; off >= 1; off >>= 1) {
            as += __shfl_down(as, off);
            at += __shfl_down(at, off);
            sq += __shfl_down(sq, off);
        }
        if ((tid & 15) == 0 && valid) {
            const int g16 = k >> 4;
            float* slot = part + (((size_t)b * NPF + g16) * NPAIR + p) * 3;
            slot[0] = as; slot[1] = at; slot[2] = sq;
        }
    }

    // ---- completion handshake: last 16 blocks take one row each ----
    __threadfence();            // release this block's part writes (device scope)
    __syncthreads();            // all lanes' stores drained (vmcnt at barrier)
    if (tid == 0) {
        unsigned old = atomicAdd(counter, 1u);
        myrow = (old >= (unsigned)(NBLOCKS - BATCH))
                    ? (int)(old - (unsigned)(NBLOCKS - BATCH)) : -1;
    }
    __syncthreads();
    const int row = myrow;
    if (row < 0) return;
    __threadfence();            // acquire: see all other blocks' part writes
    row_topk(part, row, smem, out, tid);
}

// ---------------------------------------------------------------------------
extern "C" void kernel_launch(void* const* d_in, const int* in_sizes, int n_in,
                              void* d_out, int out_size, void* d_ws, size_t ws_size,
                              hipStream_t stream)
{
    const float* s_in = (const float*)d_in[0];
    const float* t_in = (const float*)d_in[1];
    const float* g_in = (const float*)d_in[2];
    float* out = (float*)d_out;

    float* part = (float*)d_ws;                               // 16*33*513*3 floats
    unsigned* counter = (unsigned*)(part + (size_t)BATCH * NPF * NPAIR * 3);

    hipMemsetAsync(out, 0, (size_t)out_size * sizeof(float), stream);
    hipMemsetAsync(counter, 0, sizeof(unsigned), stream);

    dim3 g1(NPAIR, BATCH);
    fused_stft_topk_kernel<<<g1, 256, 0, stream>>>(s_in, t_in, g_in, part, counter, out);
}

// Round 10
// 184.080 us; speedup vs baseline: 5.0425x; 5.0425x over previous
//
#include <hip/hip_runtime.h>
#include <hip/hip_bf16.h>
#include <math.h>

// Problem constants (fixed by setup_inputs)
#define BATCH 16
#define LEN   262144
#define HOP   256
#define PADW  512          // n_fft/2
#define NFREQ 513          // rfft bins
#define NFRM  1025         // frames
#define NPAIR 513          // frame pairs (2 frames per FFT)
#define NPT   65           // time patches
#define NPF   33           // freq patches
#define NPATCH 2145        // 33*65
#define TOPK  643          // int(2145*0.3)
#define EPSV  1e-8f

// LDS bank-conflict swizzle: float2 element i lives at phys i^((i>>4)&15).
// NOTE: for j<4 and i0=4t, SW(i0+j) = SW(i0) ^ j (XOR, not +j — R7 bug).
#define SW(i) ((i) ^ (((i) >> 4) & 15))

__device__ __forceinline__ int reflect_idx(int g) {
    g = (g < 0) ? -g : g;
    g = (g >= LEN) ? (2 * LEN - 2 - g) : g;
    return g;
}

__device__ __forceinline__ void load_pack_edge(float2* xs,
    const float* __restrict__ re_src, const float* __restrict__ im_src,
    int startRe, int startIm, int tid)
{
    #pragma unroll
    for (int m = 0; m < 4; ++m) {
        const int i = tid + 256 * m;
        xs[SW(i)] = make_float2(re_src[reflect_idx(startRe + i)],
                                im_src[reflect_idx(startIm + i)]);
    }
    __syncthreads();
}

__device__ __forceinline__ void load_pack_fast(float2* xs,
    const float* __restrict__ re_src, const float* __restrict__ im_src,
    int startRe, int startIm, int tid)
{
    const float4 r4 = *reinterpret_cast<const float4*>(re_src + startRe + 4 * tid);
    const float4 i4 = *reinterpret_cast<const float4*>(im_src + startIm + 4 * tid);
    const int base = SW(4 * tid);
    xs[base ^ 0] = make_float2(r4.x, i4.x);   // SW(4t+j) = SW(4t) ^ j
    xs[base ^ 1] = make_float2(r4.y, i4.y);
    xs[base ^ 2] = make_float2(r4.z, i4.z);
    xs[base ^ 3] = make_float2(r4.w, i4.w);
    __syncthreads();
}

// 1024-pt radix-4 DIF complex FFT. Natural input, base-4 digit-reversed output.
__device__ __forceinline__ void fft1024(float2* xs, const float2* tw, float2 w0, int tid) {
    #pragma unroll
    for (int s = 0; s < 5; ++s) {
        const int lenlog = 10 - 2 * s;
        const int q      = 1 << (lenlog - 2);
        const int pos    = tid & (q - 1);
        const int blk    = tid >> (lenlog - 2);
        const int i0     = (blk << lenlog) + pos;

        float2 a  = xs[SW(i0)];
        float2 bb = xs[SW(i0 + q)];
        float2 c  = xs[SW(i0 + 2 * q)];
        float2 d  = xs[SW(i0 + 3 * q)];

        const float t0x = a.x + c.x,  t0y = a.y + c.y;
        const float t1x = a.x - c.x,  t1y = a.y - c.y;
        const float t2x = bb.x + d.x, t2y = bb.y + d.y;
        const float t3x = bb.x - d.x, t3y = bb.y - d.y;

        const float y0x = t0x + t2x, y0y = t0y + t2y;
        const float y1x = t1x + t3y, y1y = t1y - t3x;
        const float y2x = t0x - t2x, y2y = t0y - t2y;
        const float y3x = t1x - t3y, y3y = t1y + t3x;

        if (s == 4) {
            const int o = SW(i0);
            xs[o ^ 0] = make_float2(y0x, y0y);
            xs[o ^ 1] = make_float2(y1x, y1y);
            xs[o ^ 2] = make_float2(y2x, y2y);
            xs[o ^ 3] = make_float2(y3x, y3y);
        } else {
            const float2 w1 = (s == 0) ? w0 : tw[SW(pos << (2 * s))];
            const float2 w2 = make_float2(w1.x * w1.x - w1.y * w1.y, 2.0f * w1.x * w1.y);
            const float2 w3 = make_float2(w2.x * w1.x - w2.y * w1.y, w2.x * w1.y + w2.y * w1.x);
            xs[SW(i0)]         = make_float2(y0x, y0y);
            xs[SW(i0 + q)]     = make_float2(y1x * w1.x - y1y * w1.y, y1x * w1.y + y1y * w1.x);
            xs[SW(i0 + 2 * q)] = make_float2(y2x * w2.x - y2y * w2.y, y2x * w2.y + y2y * w2.x);
            xs[SW(i0 + 3 * q)] = make_float2(y3x * w3.x - y3y * w3.y, y3x * w3.y + y3y * w3.x);
        }
        __syncthreads();
    }
}

__device__ __forceinline__ void unpack_k(const float2* xs, int k,
                                         float& mx, float& my)
{
    const unsigned rk = __brev((unsigned)k) >> 22;
    const unsigned pk = ((rk & 0x155u) << 1) | ((rk & 0x2AAu) >> 1);
    const unsigned mI = (unsigned)(1024 - k) & 1023u;
    const unsigned rm = __brev(mI) >> 22;
    const unsigned pm = ((rm & 0x155u) << 1) | ((rm & 0x2AAu) >> 1);
    const float2 Zk = xs[SW(pk)];
    const float2 Zm = xs[SW(pm)];
    const float ar = Zk.x + Zm.x, ai = Zk.y - Zm.y;   // 2*X[k]
    const float br = Zk.y + Zm.y, bi = Zk.x - Zm.x;   // 2*Y[k]
    mx = fmaxf(0.5f * sqrtf(ar * ar + ai * ai), EPSV);
    my = fmaxf(0.5f * sqrtf(br * br + bi * bi), EPSV);
}

// ---------------------------------------------------------------------------
// Fused STFT + patch-partials, register-staged. Block = (pair p, batch b).
// Thread tid owns bins {tid, tid+256, tid+512}; s,t,g magnitudes meet in
// registers. part layout [b][g16][pair][3]: a patch's 8 pair-partials are 24
// contiguous floats for the topk kernel.  (Identical to the verified R8 kernel.)
// ---------------------------------------------------------------------------
__global__ __launch_bounds__(256) void stft_pair_kernel(
    const float* __restrict__ s_in, const float* __restrict__ t_in,
    const float* __restrict__ g_in,
    float* __restrict__ part)
{
    __shared__ float2 xs[1024];
    __shared__ float2 tw[256];

    const int tid = threadIdx.x;
    const int p   = blockIdx.x;   // 0..512
    const int b   = blockIdx.y;   // 0..15

    const float* sp = s_in + (size_t)b * LEN;
    const float* tp = t_in + (size_t)b * LEN;
    const float* gp = g_in + (size_t)b * LEN;

    float2 w0;
    {
        float sv, cv;
        sincosf(-6.283185307179586476925f * (float)tid * (1.0f / 1024.0f), &sv, &cv);
        w0 = make_float2(cv, sv);
        tw[SW(tid)] = w0;
    }

    const bool hasB  = (2 * p + 1) < NFRM;
    const bool fast  = (p >= 1) && (p <= 510);
    const int startA = 2 * p * HOP - PADW;
    const int startB = startA + HOP;

    float sA[3], tA[3], sB[3], tB[3];

    if (fast) load_pack_fast(xs, sp, tp, startA, startA, tid);
    else      load_pack_edge(xs, sp, tp, startA, startA, tid);
    fft1024(xs, tw, w0, tid);
    #pragma unroll
    for (int it = 0; it < 3; ++it) {
        const int k = tid + 256 * it;
        sA[it] = 0.0f; tA[it] = 0.0f;
        if (k <= 512) unpack_k(xs, k, sA[it], tA[it]);
    }
    __syncthreads();

    if (fast) load_pack_fast(xs, sp, tp, startB, startB, tid);
    else      load_pack_edge(xs, sp, tp, startB, startB, tid);
    fft1024(xs, tw, w0, tid);
    #pragma unroll
    for (int it = 0; it < 3; ++it) {
        const int k = tid + 256 * it;
        sB[it] = 0.0f; tB[it] = 0.0f;
        if (k <= 512) unpack_k(xs, k, sB[it], tB[it]);
    }
    __syncthreads();

    if (fast) load_pack_fast(xs, gp, gp, startA, startB, tid);
    else      load_pack_edge(xs, gp, gp, startA, startB, tid);
    fft1024(xs, tw, w0, tid);

    #pragma unroll
    for (int it = 0; it < 3; ++it) {
        const int k = tid + 256 * it;
        const bool valid = (k <= 512);
        float as = 0.0f, at = 0.0f, sq = 0.0f;
        if (valid) {
            float gA_, gB_;
            unpack_k(xs, k, gA_, gB_);
            as = fabsf(sA[it] - gA_);
            at = fabsf(tA[it] - gA_);
            sq = (sA[it] - tA[it]) * (sA[it] - tA[it]);
            if (hasB) {
                as += fabsf(sB[it] - gB_);
                at += fabsf(tB[it] - gB_);
                sq += (sB[it] - tB[it]) * (sB[it] - tB[it]);
            }
        }
        #pragma unroll
        for (int off = 8; off >= 1; off >>= 1) {
            as += __shfl_down(as, off);
            at += __shfl_down(at, off);
            sq += __shfl_down(sq, off);
        }
        if ((tid & 15) == 0 && valid) {
            const int g16 = k >> 4;
            float* slot = part + (((size_t)b * NPF + g16) * NPAIR + p) * 3;
            slot[0] = as; slot[1] = at; slot[2] = sq;
        }
    }
}

// ---------------------------------------------------------------------------
// Fused combine + top-k + final. 16 blocks (one per batch row) x 256 threads.
// Radix select with jax tie-break; each block atomically accumulates its
// row's contribution to the 4 outputs (out must be zeroed; out[1] plain-set).
// ---------------------------------------------------------------------------
__global__ __launch_bounds__(256) void topk16_kernel(
    const float* __restrict__ part,
    float* __restrict__ out)
{
    __shared__ unsigned       ukey[NPATCH];
    __shared__ float          plv[NPATCH];
    __shared__ unsigned short tIdx[NPATCH];
    __shared__ unsigned       hist[256];
    __shared__ unsigned       wtot[4];
    __shared__ int            tcnt;
    __shared__ unsigned       selB, selHi;
    __shared__ float          red[3][4];

    const int tid = threadIdx.x;
    const int b   = blockIdx.x;

    // Phase A: combine pair partials -> key + patch_loss.
    float lsum = 0.0f, lpos = 0.0f;
    for (int p2 = tid; p2 < NPATCH; p2 += 256) {
        const int fi = p2 / NPT;
        const int ti = p2 - fi * NPT;
        const float* base = part + (((size_t)b * NPF + fi) * NPAIR + ti * 8) * 3;
        float a = 0.0f, t3 = 0.0f, q = 0.0f;
        #pragma unroll
        for (int u = 0; u < 8; ++u) {
            if (ti * 8 + u < NPAIR) {
                a  += base[u * 3 + 0];
                t3 += base[u * 3 + 1];
                q  += base[u * 3 + 2];
            }
        }
        const float kg = (a - t3) * (1.0f / 256.0f);
        lsum += kg;
        lpos += (kg > 0.0f) ? 1.0f : 0.0f;
        plv[p2] = q * (1.0f / 256.0f);
        unsigned u32 = __float_as_uint(kg);
        ukey[p2] = (u32 & 0x80000000u) ? ~u32 : (u32 | 0x80000000u);
    }
    if (tid == 0) tcnt = 0;
    __syncthreads();

    // Phase B: 8-bit MSB radix select.
    unsigned prefix = 0;
    int rem = TOPK;
    #pragma unroll
    for (int pass = 0; pass < 4; ++pass) {
        const int shift = 24 - 8 * pass;
        const unsigned himask = (pass == 0) ? 0u : (0xFFFFFFFFu << (shift + 8));

        hist[tid] = 0;
        __syncthreads();
        for (int i = tid; i < NPATCH; i += 256) {
            unsigned u = ukey[i];
            if ((u & himask) == (prefix & himask))
                atomicAdd(&hist[(u >> shift) & 255u], 1u);
        }
        __syncthreads();

        const unsigned h = hist[tid];
        unsigned v = h;
        const int lane = tid & 63;
        const int w    = tid >> 6;
        #pragma unroll
        for (int off = 1; off < 64; off <<= 1) {
            unsigned tval = __shfl_down(v, off);
            if (lane + off < 64) v += tval;
        }
        if (lane == 0) wtot[w] = v;
        __syncthreads();
        unsigned addv = 0;
        for (int w2 = w + 1; w2 < 4; ++w2) addv += wtot[w2];
        v += addv;                    // suffix sum over bins >= tid
        const unsigned hi = v - h;    // suffix sum over bins >  tid
        if (v >= (unsigned)rem && hi < (unsigned)rem) { selB = (unsigned)tid; selHi = hi; }
        __syncthreads();
        prefix |= (selB << shift);
        rem -= (int)selHi;
        __syncthreads();
    }

    // Phase C: selected sums (ties at T resolved by lowest index — jax order).
    const unsigned T = prefix;
    float ssum = 0.0f;
    for (int i = tid; i < NPATCH; i += 256) {
        unsigned u = ukey[i];
        if (u > T) {
            ssum += plv[i];
        } else if (u == T) {
            int j = atomicAdd(&tcnt, 1);
            tIdx[j] = (unsigned short)i;
        }
    }
    __syncthreads();
    const int m = tcnt;
    if (m == rem) {
        for (int j = tid; j < m; j += 256) ssum += plv[tIdx[j]];
    } else {
        for (int j = tid; j < m; j += 256) {
            const int i = tIdx[j];
            int rank = 0;
            for (int q = 0; q < m; ++q) rank += (tIdx[q] < i) ? 1 : 0;
            if (rank < rem) ssum += plv[i];
        }
    }

    #pragma unroll
    for (int off = 32; off > 0; off >>= 1) {
        ssum += __shfl_down(ssum, off);
        lsum += __shfl_down(lsum, off);
        lpos += __shfl_down(lpos, off);
    }
    if ((tid & 63) == 0) {
        const int wv = tid >> 6;
        red[0][wv] = ssum; red[1][wv] = lsum; red[2][wv] = lpos;
    }
    __syncthreads();
    if (tid == 0) {
        float a = red[0][0] + red[0][1] + red[0][2] + red[0][3];
        float c = red[1][0] + red[1][1] + red[1][2] + red[1][3];
        float d = red[2][0] + red[2][1] + red[2][2] + red[2][3];
        atomicAdd(&out[0], a * (1.0f / ((float)TOPK * (float)BATCH)));
        atomicAdd(&out[2], c * (1.0f / ((float)BATCH * (float)NPATCH)));
        atomicAdd(&out[3], d * (1.0f / ((float)BATCH * (float)NPATCH)));
        if (b == 0) out[1] = (float)TOPK / (float)NPATCH;
    }
}

// ---------------------------------------------------------------------------
extern "C" void kernel_launch(void* const* d_in, const int* in_sizes, int n_in,
                              void* d_out, int out_size, void* d_ws, size_t ws_size,
                              hipStream_t stream)
{
    const float* s_in = (const float*)d_in[0];
    const float* t_in = (const float*)d_in[1];
    const float* g_in = (const float*)d_in[2];
    float* out = (float*)d_out;

    float* part = (float*)d_ws;                               // 16*33*513*3 floats

    hipMemsetAsync(out, 0, (size_t)out_size * sizeof(float), stream);

    dim3 g1(NPAIR, BATCH);
    stft_pair_kernel<<<g1, 256, 0, stream>>>(s_in, t_in, g_in, part);

    topk16_kernel<<<BATCH, 256, 0, stream>>>(part, out);
}